// Round 1
// baseline (767.284 us; speedup 1.0000x reference)
//
#include <hip/hip_runtime.h>
#include <stdint.h>

#define NPROP   128
#define C_ALL   19
#define NCLS    18
#define M_TOTAL 400000
#define NPTS    65536
#define ROW_WORDS (NPTS / 32)   // 2048 u32 words = 8 KiB bitmap

// ---- workspace layout ----
struct WS {
    unsigned int counts[NPROP];
    unsigned int offsets[NPROP + 1];
    unsigned int cursor[NPROP];
    float        spred[NCLS * NPROP];
    unsigned int keepA[NCLS * NPROP];
    unsigned long long sorted[M_TOTAL];   // (bits18 << 16) | point_id16
};

// ---- kernel 1: per-proposal softmax + score-based keep flags; init counters ----
__global__ void prep_kernel(const float* __restrict__ cls_scores,
                            const float* __restrict__ scores,
                            WS* ws) {
    int p = threadIdx.x;
    if (p >= NPROP) return;
    ws->counts[p] = 0;

    float row[C_ALL];
    float mx = -3.4e38f;
    #pragma unroll
    for (int i = 0; i < C_ALL; ++i) {
        row[i] = cls_scores[p * C_ALL + i];
        mx = fmaxf(mx, row[i]);
    }
    float s = 0.0f;
    #pragma unroll
    for (int i = 0; i < C_ALL; ++i) {
        row[i] = __expf(row[i] - mx);
        s += row[i];
    }
    float inv = 1.0f / s;
    #pragma unroll
    for (int c = 0; c < NCLS; ++c) {
        float soft = row[c] * inv;
        float sc = scores[p * C_ALL + c];
        sc = fminf(fmaxf(sc, 0.0f), 1.0f);
        float sp = sc * soft;
        ws->spred[c * NPROP + p] = sp;
        ws->keepA[c * NPROP + p] = (soft > 0.001f && sp > -1.0f) ? 1u : 0u;
    }
}

// ---- kernel 2: histogram of proposal ids ----
__global__ void count_kernel(const int* __restrict__ prop_ids, WS* ws) {
    int m = blockIdx.x * blockDim.x + threadIdx.x;
    if (m < M_TOTAL) atomicAdd(&ws->counts[prop_ids[m]], 1u);
}

// ---- kernel 3: exclusive prefix sum (trivial size) ----
__global__ void prefix_kernel(WS* ws) {
    if (threadIdx.x == 0 && blockIdx.x == 0) {
        unsigned int acc = 0;
        for (int p = 0; p < NPROP; ++p) {
            ws->offsets[p] = acc;
            ws->cursor[p]  = acc;
            acc += ws->counts[p];
        }
        ws->offsets[NPROP] = acc;
    }
}

// ---- kernel 4: bucket entries by proposal, packing point id + 18 class bits ----
__global__ void scatter_kernel(const float* __restrict__ mask_scores,
                               const int* __restrict__ prop_ids,
                               const int* __restrict__ point_ids,
                               WS* ws) {
    int m = blockIdx.x * blockDim.x + threadIdx.x;
    if (m >= M_TOTAL) return;
    const float* r = mask_scores + (size_t)m * C_ALL;
    unsigned int bits = 0;
    #pragma unroll
    for (int c = 0; c < NCLS; ++c)
        bits |= (r[c] > -0.5f ? 1u : 0u) << c;
    unsigned int pos = atomicAdd(&ws->cursor[prop_ids[m]], 1u);
    ws->sorted[pos] = ((unsigned long long)bits << 16) | (unsigned int)(point_ids[m] & 0xFFFF);
}

// ---- kernel 5: one block per (class, proposal): LDS bitmap -> popcount -> row write ----
__global__ __launch_bounds__(256) void main_kernel(const WS* __restrict__ ws,
                                                   float* __restrict__ out) {
    __shared__ unsigned int bm[ROW_WORDS];
    __shared__ unsigned int s_cnt;
    const int p = blockIdx.x;
    const int c = blockIdx.y;
    const int t = threadIdx.x;

    #pragma unroll
    for (int i = 0; i < ROW_WORDS / 256; ++i) bm[t + i * 256] = 0;
    if (t == 0) s_cnt = 0;
    __syncthreads();

    const unsigned int beg = ws->offsets[p];
    const unsigned int end = ws->offsets[p + 1];
    const unsigned long long cbit = 1ull << (16 + c);
    for (unsigned int i = beg + t; i < end; i += 256) {
        unsigned long long e = ws->sorted[i];
        if (e & cbit) {
            unsigned int pt = (unsigned int)(e & 0xFFFFull);
            atomicOr(&bm[pt >> 5], 1u << (pt & 31));
        }
    }
    __syncthreads();

    unsigned int local = 0;
    #pragma unroll
    for (int i = 0; i < ROW_WORDS / 256; ++i) local += __popc(bm[t + i * 256]);
    atomicAdd(&s_cnt, local);
    __syncthreads();

    const int cp = c * NPROP + p;
    const bool keep = (ws->keepA[cp] != 0u) && (s_cnt >= 100u);

    float4* __restrict__ r4 = (float4*)(out + ((size_t)cp << 16));
    if (keep) {
        #pragma unroll
        for (int j = 0; j < (NPTS / 4) / 256; ++j) {
            int idx = j * 256 + t;                 // float4 index within row
            unsigned int w = bm[idx >> 3];         // 8 float4 per u32 word
            unsigned int nib = (w >> ((idx & 7) * 4)) & 0xFu;
            float4 v;
            v.x = (nib & 1u) ? 1.0f : 0.0f;
            v.y = (nib & 2u) ? 1.0f : 0.0f;
            v.z = (nib & 4u) ? 1.0f : 0.0f;
            v.w = (nib & 8u) ? 1.0f : 0.0f;
            r4[idx] = v;
        }
    } else {
        const float4 z = make_float4(0.f, 0.f, 0.f, 0.f);
        #pragma unroll
        for (int j = 0; j < (NPTS / 4) / 256; ++j)
            r4[j * 256 + t] = z;
    }

    if (t == 0) {
        float* outCS = out + (size_t)NCLS * NPROP * NPTS;
        float* outK  = outCS + NCLS * NPROP;
        float* outS  = outK  + NCLS * NPROP;
        outCS[cp] = keep ? ws->spred[cp] : 0.0f;
        outK[cp]  = keep ? 1.0f : 0.0f;
        outS[cp]  = (float)(c + 1);
    }
}

extern "C" void kernel_launch(void* const* d_in, const int* in_sizes, int n_in,
                              void* d_out, int out_size, void* d_ws, size_t ws_size,
                              hipStream_t stream) {
    const float* cls_scores  = (const float*)d_in[0];
    const float* scores      = (const float*)d_in[1];
    const float* mask_scores = (const float*)d_in[2];
    const int*   prop_ids    = (const int*)d_in[3];
    const int*   point_ids   = (const int*)d_in[4];
    // d_in[5] = num_points scalar (65536), compile-time constant here.

    WS* ws = (WS*)d_ws;
    float* out = (float*)d_out;

    prep_kernel<<<1, NPROP, 0, stream>>>(cls_scores, scores, ws);

    const int threads = 256;
    const int blocksM = (M_TOTAL + threads - 1) / threads;
    count_kernel<<<blocksM, threads, 0, stream>>>(prop_ids, ws);
    prefix_kernel<<<1, 64, 0, stream>>>(ws);
    scatter_kernel<<<blocksM, threads, 0, stream>>>(mask_scores, prop_ids, point_ids, ws);

    dim3 grid(NPROP, NCLS);
    main_kernel<<<grid, 256, 0, stream>>>(ws, out);
}

// Round 2
// 172.349 us; speedup vs baseline: 4.4519x; 4.4519x over previous
//
#include <hip/hip_runtime.h>
#include <stdint.h>

#define NPROP   128
#define C_ALL   19
#define NCLS    18
#define M_TOTAL 400000
#define NPTS    65536
#define CP      (NCLS * NPROP)
#define PTS_PER_CHUNK 8192
#define NCHUNK  (NPTS / PTS_PER_CHUNK)   // 8

// ---- workspace: ~32.03 MB ----
struct WS {
    float        spred[CP];
    unsigned int keepA[CP];
    unsigned int pointnum[CP];
    unsigned int dense[(size_t)NPROP * NPTS];   // 18 class bits per (p, pt)
};

// ---- zero dense plane + pointnum (grid-stride uint4) ----
__global__ void zero_kernel(WS* ws) {
    const size_t tid = (size_t)blockIdx.x * blockDim.x + threadIdx.x;
    const size_t stride = (size_t)gridDim.x * blockDim.x;
    uint4* d4 = (uint4*)ws->dense;
    const size_t n4 = (size_t)NPROP * NPTS / 4;   // 2,097,152
    const uint4 z = make_uint4(0u, 0u, 0u, 0u);
    for (size_t j = tid; j < n4; j += stride) d4[j] = z;
    if (tid < CP) ws->pointnum[tid] = 0;
}

// ---- per-proposal softmax + score-based keep preconditions ----
__global__ void prep_kernel(const float* __restrict__ cls_scores,
                            const float* __restrict__ scores,
                            WS* ws) {
    int p = threadIdx.x;
    if (p >= NPROP) return;
    float row[C_ALL];
    float mx = -3.4e38f;
    #pragma unroll
    for (int i = 0; i < C_ALL; ++i) {
        row[i] = cls_scores[p * C_ALL + i];
        mx = fmaxf(mx, row[i]);
    }
    float s = 0.0f;
    #pragma unroll
    for (int i = 0; i < C_ALL; ++i) {
        row[i] = __expf(row[i] - mx);
        s += row[i];
    }
    float inv = 1.0f / s;
    #pragma unroll
    for (int c = 0; c < NCLS; ++c) {
        float soft = row[c] * inv;
        float sc = scores[p * C_ALL + c];
        sc = fminf(fmaxf(sc, 0.0f), 1.0f);
        float sp = sc * soft;
        ws->spred[c * NPROP + p] = sp;
        ws->keepA[c * NPROP + p] = (soft > 0.001f && sp > -1.0f) ? 1u : 0u;
    }
}

// ---- one pass over M: pack 18 threshold bits, atomicOr into dense ----
__global__ void scatter_kernel(const float* __restrict__ mask_scores,
                               const int* __restrict__ prop_ids,
                               const int* __restrict__ point_ids,
                               WS* ws) {
    int m = blockIdx.x * blockDim.x + threadIdx.x;
    if (m >= M_TOTAL) return;
    const float* r = mask_scores + (size_t)m * C_ALL;
    unsigned int bits = 0;
    #pragma unroll
    for (int c = 0; c < NCLS; ++c)
        bits |= (unsigned int)(r[c] > -0.5f) << c;
    const size_t addr = ((size_t)prop_ids[m] << 16) | (unsigned int)point_ids[m];
    atomicOr(&ws->dense[addr], bits);
}

// ---- popcount dense -> pointnum[c][p] ----
__global__ __launch_bounds__(256) void count_kernel(WS* ws) {
    __shared__ unsigned int cnt[NCLS];
    const int p = blockIdx.x;
    const int chunk = blockIdx.y;
    const int t = threadIdx.x;
    if (t < NCLS) cnt[t] = 0;
    __syncthreads();

    const unsigned int* base = ws->dense + ((size_t)p << 16) + chunk * (NPTS / 4);
    unsigned int local[NCLS] = {0};
    for (int i = t; i < NPTS / 4; i += 256) {
        unsigned int w = base[i];
        #pragma unroll
        for (int c = 0; c < NCLS; ++c) local[c] += (w >> c) & 1u;
    }
    #pragma unroll
    for (int c = 0; c < NCLS; ++c) {
        unsigned int v = local[c];
        #pragma unroll
        for (int off = 32; off > 0; off >>= 1) v += __shfl_down(v, off, 64);
        if ((t & 63) == 0) atomicAdd(&cnt[c], v);
    }
    __syncthreads();
    if (t < NCLS) atomicAdd(&ws->pointnum[t * NPROP + p], cnt[t]);
}

// ---- stage dense chunk in LDS once, emit all 18 class rows + small outputs ----
__global__ __launch_bounds__(256) void write_kernel(const WS* __restrict__ ws,
                                                    float* __restrict__ out) {
    __shared__ unsigned int lds[PTS_PER_CHUNK];        // 32 KiB
    __shared__ float sk[NCLS];
    const int p = blockIdx.x;
    const int chunk = blockIdx.y;
    const int t = threadIdx.x;

    // load 8192 dense words (one per point) into LDS, uint4-vectorized
    const uint4* src4 = (const uint4*)(ws->dense + ((size_t)p << 16) + chunk * PTS_PER_CHUNK);
    uint4* lds4 = (uint4*)lds;
    #pragma unroll
    for (int j = 0; j < (PTS_PER_CHUNK / 4) / 256; ++j)   // 8 iters
        lds4[j * 256 + t] = src4[j * 256 + t];

    if (t < NCLS) {
        const int cp = t * NPROP + p;
        const bool k = (ws->keepA[cp] != 0u) && (ws->pointnum[cp] >= 100u);
        sk[t] = k ? 1.0f : 0.0f;
        if (chunk == 0) {
            float* outCS = out + (size_t)CP * NPTS;
            float* outK  = outCS + CP;
            float* outS  = outK  + CP;
            outCS[cp] = k ? ws->spred[cp] : 0.0f;
            outK[cp]  = k ? 1.0f : 0.0f;
            outS[cp]  = (float)(t + 1);
        }
    }
    __syncthreads();

    const float4 z = make_float4(0.f, 0.f, 0.f, 0.f);
    #pragma unroll 1
    for (int c = 0; c < NCLS; ++c) {
        float4* dst = (float4*)(out + (((size_t)(c * NPROP + p)) << 16)) +
                      chunk * (PTS_PER_CHUNK / 4);
        if (sk[c] != 0.0f) {
            #pragma unroll
            for (int j = 0; j < (PTS_PER_CHUNK / 4) / 256; ++j) {  // 8 iters
                const int idx = j * 256 + t;
                uint4 w = lds4[idx];
                float4 v;
                v.x = (w.x >> c) & 1u ? 1.0f : 0.0f;
                v.y = (w.y >> c) & 1u ? 1.0f : 0.0f;
                v.z = (w.z >> c) & 1u ? 1.0f : 0.0f;
                v.w = (w.w >> c) & 1u ? 1.0f : 0.0f;
                dst[idx] = v;
            }
        } else {
            #pragma unroll
            for (int j = 0; j < (PTS_PER_CHUNK / 4) / 256; ++j)
                dst[j * 256 + t] = z;
        }
    }
}

extern "C" void kernel_launch(void* const* d_in, const int* in_sizes, int n_in,
                              void* d_out, int out_size, void* d_ws, size_t ws_size,
                              hipStream_t stream) {
    const float* cls_scores  = (const float*)d_in[0];
    const float* scores      = (const float*)d_in[1];
    const float* mask_scores = (const float*)d_in[2];
    const int*   prop_ids    = (const int*)d_in[3];
    const int*   point_ids   = (const int*)d_in[4];

    WS* ws = (WS*)d_ws;
    float* out = (float*)d_out;

    zero_kernel<<<2048, 256, 0, stream>>>(ws);
    prep_kernel<<<1, NPROP, 0, stream>>>(cls_scores, scores, ws);

    const int blocksM = (M_TOTAL + 255) / 256;
    scatter_kernel<<<blocksM, 256, 0, stream>>>(mask_scores, prop_ids, point_ids, ws);

    count_kernel<<<dim3(NPROP, 4), 256, 0, stream>>>(ws);
    write_kernel<<<dim3(NPROP, NCHUNK), 256, 0, stream>>>(ws, out);
}